// Round 8
// baseline (148.406 us; speedup 1.0000x reference)
//
#include <hip/hip_runtime.h>
#include <hip/hip_bf16.h>
#include <math.h>

// TopicRouter, single fused kernel:
//  logits[B,8] = h @ gate_w^T + b, plus per-row top-2 + softmax, one pass.
//  HBM-bound in principle (96 MB of h) — but R7 exposed a hidden second
//  roofline: the LDS gate read. One row per wave-iter read 24.5 KB of gate
//  LDS per 3 KB of HBM (8:1); sustaining HBM at 10 B/cy/CU needs ~80 B/cy
//  of ds_read_b128 vs the ~85 B/cy ceiling (m134) -> DS pipe ~96% busy
//  before shuffles. Router stuck at ~40 us regardless of occupancy.
//
//  R8: FOUR ROWS PER WAVE-ITERATION. Each gate value fetched from LDS feeds
//  4 rows' FMAs -> DS:HBM ratio drops 8:1 -> 2:1 (~52% DS util at full HBM
//  rate). Reduce/top-2 uses the packed-pair scheme (rows packed at lane
//  bit3): per 2 rows = 7+7 group-folds (xor1/2/4) + 2 xor8 folds + pack +
//  xor16/32 + 12-shuffle packed top-2.
//  Spill discipline (R4-R6 lesson): __launch_bounds__(256,2) = 256-reg
//  budget, live state ~105 regs (cv 48 + acc 32 + misc) -> no spill, and
//  actual usage <=128 should give 4 waves/SIMD, 16 waves/CU (LDS caps at
//  4 blocks/CU x 24 KB = 96 KB). In-place prefetch: cv reloaded right after
//  the FMA phase (zero extra regs), flying under reduce/top-2/writes.
//  Top-2 comparator matches lax.top_k (strict >, lower index wins ties).
//  Assumes B % 4 == 0 (B = 32768).

constexpr int D  = 768;
constexpr int E  = 8;
constexpr int D4 = D / 4;          // 192 float4 per row
constexpr int BLOCK  = 256;        // 4 waves
constexpr int GRID_A = 1024;       // 4 blocks/CU x 256 CU; 4096 waves

__device__ __forceinline__ float dot4acc(float4 a, float4 b, float acc) {
    acc = fmaf(a.x, b.x, acc);
    acc = fmaf(a.y, b.y, acc);
    acc = fmaf(a.z, b.z, acc);
    acc = fmaf(a.w, b.w, acc);
    return acc;
}

// Fold a[8] (per-expert partials) within each 8-lane group via xor 1/2/4.
// Returns this lane's group-partial for expert e = bitrev3(lane&7).
__device__ __forceinline__ float group_fold8(float a[8], int lane) {
    {   // xor 1: 8 -> 4 values
        const bool hi = lane & 1;
#pragma unroll
        for (int j = 0; j < 4; ++j) {
            float send = hi ? a[j] : a[j + 4];
            float recv = __shfl_xor(send, 1, 64);
            float keep = hi ? a[j + 4] : a[j];
            a[j] = keep + recv;
        }
    }
    {   // xor 2: 4 -> 2
        const bool hi = lane & 2;
#pragma unroll
        for (int j = 0; j < 2; ++j) {
            float send = hi ? a[j] : a[j + 2];
            float recv = __shfl_xor(send, 2, 64);
            float keep = hi ? a[j + 2] : a[j];
            a[j] = keep + recv;
        }
    }
    {   // xor 4: 2 -> 1
        const bool hi = lane & 4;
        float send = hi ? a[0] : a[1];
        float recv = __shfl_xor(send, 4, 64);
        float keep = hi ? a[1] : a[0];
        a[0] = keep + recv;
    }
    return a[0];
}

// Finish two rows: full reduce (packed at lane bit3), logits write, fused
// packed top-2 + softmax write. rowa must be even-ish only in the sense that
// rows rowa, rowa+1 are written.
__device__ __forceinline__ void finish_pair(float pa, float pb, float bias,
                                            int lane, int e_lane, int rowa,
                                            float* __restrict__ out_logits,
                                            float* __restrict__ out_idx,
                                            float* __restrict__ out_w) {
    // Cross-group reduce. xor8 fold per row -> 16-lane-slab partials.
    pa += __shfl_xor(pa, 8, 64);
    pb += __shfl_xor(pb, 8, 64);
    // Pack rows at bit3 (even 8-groups: row a, odd: row b); xor16/32 stay
    // within the same bit3 parity, so each row sums over its 4 slabs.
    float q = (lane & 8) ? pb : pa;
    q += __shfl_xor(q, 16, 64);
    q += __shfl_xor(q, 32, 64);
    float v = q + bias;

    // Lanes 0..15 write both rows' logits as one contiguous 64 B chunk.
    if (lane < 16) out_logits[(size_t)rowa * 8 + (lane & 8) + e_lane] = v;

    // Packed top-2 within each 8-lane group (even groups: row a, odd: row b).
    // Comparator matches lax.top_k: strict >, lower expert index wins ties.
    float t0 = v;          int x0 = e_lane;
    float t1 = -INFINITY;  int x1 = E;      // sentinel
#pragma unroll
    for (int m = 1; m <= 4; m <<= 1) {
        float w0 = __shfl_xor(t0, m, 64);
        int   j0 = __shfl_xor(x0, m, 64);
        float w1 = __shfl_xor(t1, m, 64);
        int   j1 = __shfl_xor(x1, m, 64);
        bool aFirst = (t0 > w0) || (t0 == w0 && x0 < j0);
        float f0  = aFirst ? t0 : w0;
        int   fi0 = aFirst ? x0 : j0;
        float losT = aFirst ? w0 : t0;   // loser's first
        int   losI = aFirst ? j0 : x0;
        float winT = aFirst ? t1 : w1;   // winner's second
        int   winI = aFirst ? x1 : j1;
        bool sWin = (winT > losT) || (winT == losT && winI < losI);
        float f1  = sWin ? winT : losT;
        int   fi1 = sWin ? winI : losI;
        t0 = f0; x0 = fi0; t1 = f1; x1 = fi1;
    }

    // Lane 0 writes row a, lane 8 writes row a+1.
    if ((lane & 7) == 0 && lane < 16) {
        float tt = expf(t1 - t0);
        float w0_ = 1.0f / (1.0f + tt);
        float w1_ = tt * w0_;
        const int row = rowa + (lane >> 3);
        ((float2*)out_idx)[row] = make_float2((float)x0, (float)x1);
        ((float2*)out_w)[row]   = make_float2(w0_, w1_);
    }
}

__global__ __launch_bounds__(BLOCK, 2)
void router_fused_kernel(const float* __restrict__ h,
                         const float* __restrict__ gate_w,
                         const float* __restrict__ gate_b,
                         float* __restrict__ out_idx,
                         float* __restrict__ out_w,
                         float* __restrict__ out_logits,
                         int B) {
    const int tid    = threadIdx.x;
    const int lane   = tid & 63;
    const int wave   = tid >> 6;
    const int gwave  = blockIdx.x * (BLOCK / 64) + wave;
    const int nwaves = gridDim.x * (BLOCK / 64);

    const int l3 = lane & 7;
    const int e_lane = ((l3 & 1) << 2) | (l3 & 2) | ((l3 >> 2) & 1);  // bitrev3
    const float bias = gate_b[e_lane];

    // Gate weights in LDS: [E][D4] float4 = 24 KB, loaded cooperatively once.
    // Lane reads gsh[e*D4 + c*64 + lane]: lane-consecutive 16 B -> conflict-free.
    __shared__ float4 gsh[E * D4];
    const float4* gw4 = (const float4*)gate_w;
#pragma unroll
    for (int i = 0; i < (E * D4) / BLOCK; ++i)
        gsh[i * BLOCK + tid] = gw4[i * BLOCK + tid];
    __syncthreads();

    const float4* h4 = (const float4*)h;
    const int nquads = B >> 2;       // B % 4 == 0 (B = 32768)

    int q = gwave;
    if (q >= nquads) return;

    // Prime: load rows 4q..4q+3 into cv (3 float4 per row per lane).
    float4 cv[4][3];
    {
        const float4* hp = h4 + (size_t)(4 * q) * D4 + lane;
#pragma unroll
        for (int r = 0; r < 4; ++r)
#pragma unroll
            for (int c = 0; c < 3; ++c)
                cv[r][c] = hp[r * D4 + c * 64];
    }

    while (true) {
        const int qn = q + nwaves;
        const bool more = (qn < nquads);       // wave-uniform branch

        // FMA phase: each gate value read from LDS feeds 4 rows (2:1 DS:HBM).
        float acc[4][E];
#pragma unroll
        for (int r = 0; r < 4; ++r)
#pragma unroll
            for (int e = 0; e < E; ++e) acc[r][e] = 0.0f;

#pragma unroll
        for (int c = 0; c < 3; ++c) {
#pragma unroll
            for (int e = 0; e < E; ++e) {
                const float4 g = gsh[e * D4 + c * 64 + lane];
#pragma unroll
                for (int r = 0; r < 4; ++r)
                    acc[r][e] = dot4acc(cv[r][c], g, acc[r][e]);
            }
        }

        // In-place prefetch: reload cv with the next quad NOW (zero extra
        // regs); loads fly under the reduce/top-2/output writes below.
        if (more) {
            const float4* hp = h4 + (size_t)(4 * qn) * D4 + lane;
#pragma unroll
            for (int r = 0; r < 4; ++r)
#pragma unroll
                for (int c = 0; c < 3; ++c)
                    cv[r][c] = hp[r * D4 + c * 64];
        }

        // Group-fold all 4 rows (xor1/2/4 within 8-lane groups), then finish
        // as two packed pairs.
        float p0 = group_fold8(acc[0], lane);
        float p1 = group_fold8(acc[1], lane);
        float p2 = group_fold8(acc[2], lane);
        float p3 = group_fold8(acc[3], lane);

        const int rbase = 4 * q;
        finish_pair(p0, p1, bias, lane, e_lane, rbase,     out_logits, out_idx, out_w);
        finish_pair(p2, p3, bias, lane, e_lane, rbase + 2, out_logits, out_idx, out_w);

        if (!more) break;
        q = qn;
    }
}

extern "C" void kernel_launch(void* const* d_in, const int* in_sizes, int n_in,
                              void* d_out, int out_size, void* d_ws, size_t ws_size,
                              hipStream_t stream) {
    const float* h      = (const float*)d_in[0];
    const float* gate_w = (const float*)d_in[1];
    const float* gate_b = (const float*)d_in[2];

    const int B = in_sizes[0] / D;   // 32768

    float* out        = (float*)d_out;
    float* out_idx    = out;                       // [B,2] indices as float
    float* out_w      = out + (size_t)B * 2;       // [B,2] weights
    float* out_logits = out + (size_t)B * 4;       // [B,8] logits

    router_fused_kernel<<<dim3(GRID_A), dim3(BLOCK), 0, stream>>>(
        h, gate_w, gate_b, out_idx, out_w, out_logits, B);
}